// Round 4
// baseline (659.339 us; speedup 1.0000x reference)
//
#include <hip/hip_runtime.h>

#define N_NODES  100000
#define N_EDGES  1250000
#define N_GRAPHS 1024
#define NB       ((N_NODES + 127) >> 7)   // 782 buckets of 128 nodes

// ---- bf16 helpers (round-to-nearest-even) ----
__device__ __forceinline__ float bflo(unsigned int w) { return __uint_as_float(w << 16); }
__device__ __forceinline__ float bfhi(unsigned int w) { return __uint_as_float(w & 0xffff0000u); }
__device__ __forceinline__ unsigned short f2bf(float f) {
  unsigned int u = __float_as_uint(f);
  u = (u + 0x7fffu + ((u >> 16) & 1u)) >> 16;
  return (unsigned short)u;
}

// ---------------- embed + linear (16 -> 32) + relu -> bf16 ----------------
__global__ void k_embed_lin(const int* __restrict__ tok,
                            const float* __restrict__ semb,
                            const float* __restrict__ cemb,
                            const float* __restrict__ lw,   // [32,16]
                            const float* __restrict__ lb,   // [32]
                            unsigned short* __restrict__ x1) {  // [N,32] bf16
  int i = blockIdx.x * blockDim.x + threadIdx.x;
  if (i >= N_NODES) return;
  int s = tok[2 * i], c = tok[2 * i + 1];
  float e[16];
#pragma unroll
  for (int k = 0; k < 8; ++k) { e[k] = semb[s * 8 + k]; e[8 + k] = cemb[c * 8 + k]; }
  unsigned int w[16];
#pragma unroll
  for (int o = 0; o < 16; ++o) {
    float a0 = lb[2 * o], a1 = lb[2 * o + 1];
#pragma unroll
    for (int k = 0; k < 16; ++k) {
      a0 = fmaf(e[k], lw[(2 * o) * 16 + k], a0);
      a1 = fmaf(e[k], lw[(2 * o + 1) * 16 + k], a1);
    }
    a0 = fmaxf(a0, 0.f); a1 = fmaxf(a1, 0.f);
    w[o] = (unsigned int)f2bf(a0) | ((unsigned int)f2bf(a1) << 16);
  }
  uint4* d4 = (uint4*)(x1 + (size_t)i * 32);
#pragma unroll
  for (int q = 0; q < 4; ++q) d4[q] = make_uint4(w[4 * q], w[4 * q + 1], w[4 * q + 2], w[4 * q + 3]);
}

// ---------------- bucket histogram (LDS-privatized) ----------------
__global__ void k_bhist(const int* __restrict__ dst, int* __restrict__ bcnt) {
  __shared__ int lh[NB];
  for (int i = threadIdx.x; i < NB; i += blockDim.x) lh[i] = 0;
  __syncthreads();
  for (int e = blockIdx.x * blockDim.x + threadIdx.x; e < N_EDGES; e += gridDim.x * blockDim.x)
    atomicAdd(&lh[dst[e] >> 7], 1);
  __syncthreads();
  for (int i = threadIdx.x; i < NB; i += blockDim.x) {
    int v = lh[i];
    if (v) atomicAdd(&bcnt[i], v);
  }
}

// ---------------- bucket scan: bases + cursors ----------------
__global__ void k_bscan(const int* __restrict__ bcnt, int* __restrict__ bbase,
                        int* __restrict__ bcur) {
  __shared__ int s[1024];
  int t = threadIdx.x;
  int d = (t < NB) ? bcnt[t] : 0;
  s[t] = d;
  __syncthreads();
  for (int off = 1; off < 1024; off <<= 1) {
    int v = (t >= off) ? s[t - off] : 0;
    __syncthreads();
    s[t] += v;
    __syncthreads();
  }
  if (t < NB) { int excl = s[t] - d; bbase[t] = excl; bcur[t] = excl; }
}

// ---------------- bucket fill: packed (src<<7)|local_dst ----------------
__global__ void k_bfill(const int* __restrict__ src, const int* __restrict__ dst,
                        int* __restrict__ bcur, int* __restrict__ tmp) {
  int e = blockIdx.x * blockDim.x + threadIdx.x;
  if (e >= N_EDGES) return;
  int d = dst[e];
  int p = atomicAdd(&bcur[d >> 7], 1);
  tmp[p] = (src[e] << 7) | (d & 127);
}

// ------- per-bucket finalize: deg/rowstart + esrc scatter (all LDS-local) -------
__global__ void k_bfinal(const int* __restrict__ bbase, const int* __restrict__ bcnt,
                         const int* __restrict__ tmp,
                         int* __restrict__ deg, int* __restrict__ rowst,
                         int* __restrict__ esrc) {
  __shared__ int h[128], sc[128], cur[128];
  const int t = threadIdx.x;
  const int b = blockIdx.x;
  const int base = bbase[b], cnt = bcnt[b];
  if (t < 128) h[t] = 0;
  __syncthreads();
  for (int i = t; i < cnt; i += 256) atomicAdd(&h[tmp[base + i] & 127], 1);
  __syncthreads();
  if (t < 128) sc[t] = h[t];
  __syncthreads();
  for (int off = 1; off < 128; off <<= 1) {
    int v = 0;
    if (t < 128 && t >= off) v = sc[t - off];
    __syncthreads();
    if (t < 128) sc[t] += v;
    __syncthreads();
  }
  if (t < 128) {
    int excl = sc[t] - h[t];
    cur[t] = excl;
    int node = (b << 7) + t;
    if (node < N_NODES) { deg[node] = h[t]; rowst[node] = base + excl; }
  }
  __syncthreads();
  for (int i = t; i < cnt; i += 256) {
    int v = tmp[base + i];
    int p = atomicAdd(&cur[v & 127], 1);
    esrc[base + p] = v >> 7;
  }
}

// ---------------- batched gather (bf16 rows): agg[i] = sum_{j->i} x[j] ----------------
// One wave per node; 64 edge indices per coalesced load; lane-groups of DIN/4
// lanes each fetch a uint2 (4 bf16) row-slice; 16 edges' loads in flight.
template <int DIN>
__global__ void __launch_bounds__(256, 4)
k_gather(const int* __restrict__ rowstart,
         const int* __restrict__ deg,
         const int* __restrict__ esrc,
         const unsigned short* __restrict__ x,   // [N,DIN] bf16
         float* __restrict__ agg) {              // [N,DIN] f32
  constexpr int LPG = DIN / 4;            // 8 (DIN=32) / 16 (DIN=64)
  constexpr int GROUPS = 64 / LPG;        // 8 / 4
  constexpr int STEP = 16;
  constexpr int UNR = STEP / GROUPS;      // 2 / 4
  const int lane = threadIdx.x & 63;
  const int node = blockIdx.x * (blockDim.x >> 6) + (threadIdx.x >> 6);
  if (node >= N_NODES) return;
  const int sub = lane / LPG;
  const int lg = lane % LPG;
  const int rs = rowstart[node];
  const int dg = deg[node];
  float a0 = 0.f, a1 = 0.f, a2 = 0.f, a3 = 0.f;
  for (int base = 0; base < dg; base += 64) {
    const int lim = min(dg - base, 64);
    int myi = 0;
    if (lane < lim) myi = esrc[rs + base + lane];
    for (int j = 0; j < lim; j += STEP) {
      uint2 r[UNR];
      int e[UNR];
#pragma unroll
      for (int u = 0; u < UNR; ++u) {
        e[u] = j + u * GROUPS + sub;                      // always < 64
        int s = __shfl(myi, e[u]);
        r[u] = *((const uint2*)(x + (size_t)s * DIN) + lg);
      }
#pragma unroll
      for (int u = 0; u < UNR; ++u) {
        if (e[u] < lim) {
          a0 += bflo(r[u].x); a1 += bfhi(r[u].x);
          a2 += bflo(r[u].y); a3 += bfhi(r[u].y);
        }
      }
    }
  }
#pragma unroll
  for (int off = LPG; off < 64; off <<= 1) {
    a0 += __shfl_xor(a0, off);
    a1 += __shfl_xor(a1, off);
    a2 += __shfl_xor(a2, off);
    a3 += __shfl_xor(a3, off);
  }
  if (sub == 0)
    *((float4*)(agg + (size_t)node * DIN) + lg) = make_float4(a0, a1, a2, a3);
}

// ------- transform: relu(agg@Wrel^T + b + x@Wroot^T), weights in VGPRs -------
template <int DIN, bool FUSE_POOL>
__global__ void __launch_bounds__(256, 2)
k_transform(const float* __restrict__ agg,           // [N,DIN] f32
            const unsigned short* __restrict__ x,    // [N,DIN] bf16
            const float* __restrict__ wrel,          // [64,DIN]
            const float* __restrict__ brel,          // [64]
            const float* __restrict__ wroot,         // [64,DIN]
            const int* __restrict__ batch,
            void* __restrict__ outv) {  // bf16 [N,64] (conv1) or f32 [G,64] sums
  const int lane = threadIdx.x & 63;
  const int wid = blockIdx.x * (blockDim.x >> 6) + (threadIdx.x >> 6);
  const int nwaves = (gridDim.x * blockDim.x) >> 6;
  float wr[DIN], wo[DIN];
#pragma unroll
  for (int q = 0; q < DIN / 4; ++q) {
    float4 a = *((const float4*)(wrel + (size_t)lane * DIN) + q);
    wr[4 * q] = a.x; wr[4 * q + 1] = a.y; wr[4 * q + 2] = a.z; wr[4 * q + 3] = a.w;
    float4 b = *((const float4*)(wroot + (size_t)lane * DIN) + q);
    wo[4 * q] = b.x; wo[4 * q + 1] = b.y; wo[4 * q + 2] = b.z; wo[4 * q + 3] = b.w;
  }
  const float bias = brel[lane];
  for (int node = wid; node < N_NODES; node += nwaves) {
    const float4* ar = (const float4*)(agg + (size_t)node * DIN);
    const uint4* xr = (const uint4*)(x + (size_t)node * DIN);
    float acc = bias;
#pragma unroll
    for (int q = 0; q < DIN / 8; ++q) {
      uint4 bv = xr[q];                        // 8 bf16, wave-uniform broadcast
      float4 c0 = ar[2 * q], c1 = ar[2 * q + 1];
      acc = fmaf(c0.x, wr[8 * q + 0], acc);
      acc = fmaf(c0.y, wr[8 * q + 1], acc);
      acc = fmaf(c0.z, wr[8 * q + 2], acc);
      acc = fmaf(c0.w, wr[8 * q + 3], acc);
      acc = fmaf(c1.x, wr[8 * q + 4], acc);
      acc = fmaf(c1.y, wr[8 * q + 5], acc);
      acc = fmaf(c1.z, wr[8 * q + 6], acc);
      acc = fmaf(c1.w, wr[8 * q + 7], acc);
      acc = fmaf(bflo(bv.x), wo[8 * q + 0], acc);
      acc = fmaf(bfhi(bv.x), wo[8 * q + 1], acc);
      acc = fmaf(bflo(bv.y), wo[8 * q + 2], acc);
      acc = fmaf(bfhi(bv.y), wo[8 * q + 3], acc);
      acc = fmaf(bflo(bv.z), wo[8 * q + 4], acc);
      acc = fmaf(bfhi(bv.z), wo[8 * q + 5], acc);
      acc = fmaf(bflo(bv.w), wo[8 * q + 6], acc);
      acc = fmaf(bfhi(bv.w), wo[8 * q + 7], acc);
    }
    acc = fmaxf(acc, 0.f);
    if (FUSE_POOL) {
      atomicAdd((float*)outv + (size_t)batch[node] * 64 + lane, acc);
    } else {
      ((unsigned short*)outv)[(size_t)node * 64 + lane] = f2bf(acc);
    }
  }
}

// ---------------- per-graph node counts ----------------
__global__ void k_count(const int* __restrict__ batch, int* __restrict__ cnt) {
  int i = blockIdx.x * blockDim.x + threadIdx.x;
  if (i < N_NODES) atomicAdd(&cnt[batch[i]], 1);
}

// ---------------- classifier ----------------
__global__ void k_cls(const float* __restrict__ sums, const int* __restrict__ cnt,
                      const float* __restrict__ cw, const float* __restrict__ cb,
                      float* __restrict__ out) {
  int idx = blockIdx.x * blockDim.x + threadIdx.x;
  if (idx >= N_GRAPHS * 10) return;
  int g = idx / 10, c = idx - g * 10;
  float invc = 1.f / fmaxf((float)cnt[g], 1.f);
  float acc = 0.f;
#pragma unroll
  for (int d = 0; d < 64; ++d) acc = fmaf(sums[g * 64 + d], cw[c * 64 + d], acc);
  out[idx] = acc * invc + cb[c];
}

extern "C" void kernel_launch(void* const* d_in, const int* in_sizes, int n_in,
                              void* d_out, int out_size, void* d_ws, size_t ws_size,
                              hipStream_t stream) {
  const int*   tok    = (const int*)d_in[0];
  const int*   eidx   = (const int*)d_in[1];
  const int*   batch  = (const int*)d_in[2];
  const float* semb   = (const float*)d_in[3];
  const float* cemb   = (const float*)d_in[4];
  const float* lw     = (const float*)d_in[5];
  const float* lb     = (const float*)d_in[6];
  const float* w1rel  = (const float*)d_in[7];
  const float* b1     = (const float*)d_in[8];
  const float* w1root = (const float*)d_in[9];
  const float* w2rel  = (const float*)d_in[10];
  const float* b2     = (const float*)d_in[11];
  const float* w2root = (const float*)d_in[12];
  const float* cw     = (const float*)d_in[13];
  const float* cb     = (const float*)d_in[14];
  const int* src = eidx;
  const int* dst = eidx + N_EDGES;

  char* p = (char*)d_ws;
  unsigned short* x1 = (unsigned short*)p;  p += (size_t)N_NODES * 32 * 2;   // bf16
  unsigned short* x2 = (unsigned short*)p;  p += (size_t)N_NODES * 64 * 2;   // bf16
  float* aggb   = (float*)p;  p += (size_t)N_NODES * 64 * 4;
  int*   degv   = (int*)p;    p += (size_t)N_NODES * 4;
  int*   rowst  = (int*)p;    p += (size_t)N_NODES * 4;
  int*   tmp    = (int*)p;    p += (size_t)N_EDGES * 4;
  int*   esrc   = (int*)p;    p += (size_t)N_EDGES * 4;
  int*   bcnt   = (int*)p;    p += 4096;
  int*   bbase  = (int*)p;    p += 4096;
  int*   bcur   = (int*)p;    p += 4096;
  float* sums   = (float*)p;  p += (size_t)N_GRAPHS * 64 * 4;
  int*   cnt    = (int*)p;    p += (size_t)N_GRAPHS * 4;

  hipMemsetAsync(bcnt, 0, (size_t)NB * 4, stream);
  hipMemsetAsync(sums, 0, (size_t)N_GRAPHS * 64 * 4 + (size_t)N_GRAPHS * 4, stream);

  k_embed_lin<<<(N_NODES + 255) / 256, 256, 0, stream>>>(tok, semb, cemb, lw, lb, x1);

  // Bucketed CSR build (782 buckets of 128 nodes)
  k_bhist<<<306, 256, 0, stream>>>(dst, bcnt);
  k_bscan<<<1, 1024, 0, stream>>>(bcnt, bbase, bcur);
  k_bfill<<<(N_EDGES + 255) / 256, 256, 0, stream>>>(src, dst, bcur, tmp);
  k_bfinal<<<NB, 256, 0, stream>>>(bbase, bcnt, tmp, degv, rowst, esrc);

  // conv1: gather x1 -> agg, transform -> x2 (bf16)
  k_gather<32><<<N_NODES / 4, 256, 0, stream>>>(rowst, degv, esrc, x1, aggb);
  k_transform<32, false><<<512, 256, 0, stream>>>(aggb, x1, w1rel, b1, w1root, nullptr, x2);

  // conv2: gather x2 -> agg, transform + fused mean-pool sums
  k_gather<64><<<N_NODES / 4, 256, 0, stream>>>(rowst, degv, esrc, x2, aggb);
  k_count<<<(N_NODES + 255) / 256, 256, 0, stream>>>(batch, cnt);
  k_transform<64, true><<<512, 256, 0, stream>>>(aggb, x2, w2rel, b2, w2root, batch, sums);

  k_cls<<<(N_GRAPHS * 10 + 255) / 256, 256, 0, stream>>>(sums, cnt, cw, cb, (float*)d_out);
}

// Round 5
// 421.971 us; speedup vs baseline: 1.5625x; 1.5625x over previous
//
#include <hip/hip_runtime.h>

#define N_NODES  100000
#define N_EDGES  1250000
#define N_GRAPHS 1024
#define NB       ((N_NODES + 127) >> 7)   // 782 buckets of 128 nodes
#define EPB      16384                     // edges per k_bfill2 block
#define NBLK_FILL ((N_EDGES + EPB - 1) / EPB)  // 77

// ---- bf16 helpers (round-to-nearest-even) ----
__device__ __forceinline__ float bflo(unsigned int w) { return __uint_as_float(w << 16); }
__device__ __forceinline__ float bfhi(unsigned int w) { return __uint_as_float(w & 0xffff0000u); }
__device__ __forceinline__ unsigned short f2bf(float f) {
  unsigned int u = __float_as_uint(f);
  u = (u + 0x7fffu + ((u >> 16) & 1u)) >> 16;
  return (unsigned short)u;
}

// ---------------- embed + linear (16 -> 32) + relu -> bf16 ----------------
__global__ void k_embed_lin(const int* __restrict__ tok,
                            const float* __restrict__ semb,
                            const float* __restrict__ cemb,
                            const float* __restrict__ lw,   // [32,16]
                            const float* __restrict__ lb,   // [32]
                            unsigned short* __restrict__ x1) {  // [N,32] bf16
  int i = blockIdx.x * blockDim.x + threadIdx.x;
  if (i >= N_NODES) return;
  int s = tok[2 * i], c = tok[2 * i + 1];
  float e[16];
#pragma unroll
  for (int k = 0; k < 8; ++k) { e[k] = semb[s * 8 + k]; e[8 + k] = cemb[c * 8 + k]; }
  unsigned int w[16];
#pragma unroll
  for (int o = 0; o < 16; ++o) {
    float a0 = lb[2 * o], a1 = lb[2 * o + 1];
#pragma unroll
    for (int k = 0; k < 16; ++k) {
      a0 = fmaf(e[k], lw[(2 * o) * 16 + k], a0);
      a1 = fmaf(e[k], lw[(2 * o + 1) * 16 + k], a1);
    }
    a0 = fmaxf(a0, 0.f); a1 = fmaxf(a1, 0.f);
    w[o] = (unsigned int)f2bf(a0) | ((unsigned int)f2bf(a1) << 16);
  }
  uint4* d4 = (uint4*)(x1 + (size_t)i * 32);
#pragma unroll
  for (int q = 0; q < 4; ++q) d4[q] = make_uint4(w[4 * q], w[4 * q + 1], w[4 * q + 2], w[4 * q + 3]);
}

// ------- bucket histogram (LDS-privatized; global counters 64B-padded) -------
__global__ void k_bhist(const int* __restrict__ dst, int* __restrict__ bcnt) {
  __shared__ int lh[NB];
  for (int i = threadIdx.x; i < NB; i += blockDim.x) lh[i] = 0;
  __syncthreads();
  for (int e = blockIdx.x * blockDim.x + threadIdx.x; e < N_EDGES; e += gridDim.x * blockDim.x)
    atomicAdd(&lh[dst[e] >> 7], 1);
  __syncthreads();
  for (int i = threadIdx.x; i < NB; i += blockDim.x) {
    int v = lh[i];
    if (v) atomicAdd(&bcnt[i * 16], v);   // one counter per cache line
  }
}

// ---------------- bucket scan: bases + padded cursors ----------------
__global__ void k_bscan(const int* __restrict__ bcnt, int* __restrict__ bbase,
                        int* __restrict__ bcur) {
  __shared__ int s[1024];
  int t = threadIdx.x;
  int d = (t < NB) ? bcnt[t * 16] : 0;
  s[t] = d;
  __syncthreads();
  for (int off = 1; off < 1024; off <<= 1) {
    int v = (t >= off) ? s[t - off] : 0;
    __syncthreads();
    s[t] += v;
    __syncthreads();
  }
  if (t < NB) { int excl = s[t] - d; bbase[t] = excl; bcur[t * 16] = excl; }
}

// ------- bucket fill, block-privatized: LDS hist -> 1 reservation/bucket -> scatter -------
__global__ void __launch_bounds__(256)
k_bfill2(const int* __restrict__ src, const int* __restrict__ dst,
         int* __restrict__ bcur, int* __restrict__ tmp) {
  __shared__ int h[NB];
  __shared__ int cur[NB];
  const int t = threadIdx.x;
  const int start = blockIdx.x * EPB;
  const int end = min(start + EPB, N_EDGES);
  for (int i = t; i < NB; i += 256) h[i] = 0;
  __syncthreads();
  for (int e = start + t; e < end; e += 256)
    atomicAdd(&h[dst[e] >> 7], 1);
  __syncthreads();
  for (int b = t; b < NB; b += 256) {
    int c = h[b];
    cur[b] = c ? atomicAdd(&bcur[b * 16], c) : 0;   // one global atomic per (block,bucket)
  }
  __syncthreads();
  for (int e = start + t; e < end; e += 256) {
    int d = dst[e];                                 // L1/L2-hot (read in phase 1)
    int pos = atomicAdd(&cur[d >> 7], 1);           // LDS cursor
    tmp[pos] = (src[e] << 7) | (d & 127);
  }
}

// ------- per-bucket finalize: deg/rowstart + esrc scatter (all LDS-local) -------
__global__ void k_bfinal(const int* __restrict__ bbase, const int* __restrict__ bcnt,
                         const int* __restrict__ tmp,
                         int* __restrict__ deg, int* __restrict__ rowst,
                         int* __restrict__ esrc) {
  __shared__ int h[128], sc[128], cur[128];
  const int t = threadIdx.x;
  const int b = blockIdx.x;
  const int base = bbase[b], cnt = bcnt[b * 16];
  if (t < 128) h[t] = 0;
  __syncthreads();
  for (int i = t; i < cnt; i += 256) atomicAdd(&h[tmp[base + i] & 127], 1);
  __syncthreads();
  if (t < 128) sc[t] = h[t];
  __syncthreads();
  for (int off = 1; off < 128; off <<= 1) {
    int v = 0;
    if (t < 128 && t >= off) v = sc[t - off];
    __syncthreads();
    if (t < 128) sc[t] += v;
    __syncthreads();
  }
  if (t < 128) {
    int excl = sc[t] - h[t];
    cur[t] = excl;
    int node = (b << 7) + t;
    if (node < N_NODES) { deg[node] = h[t]; rowst[node] = base + excl; }
  }
  __syncthreads();
  for (int i = t; i < cnt; i += 256) {
    int v = tmp[base + i];
    int p = atomicAdd(&cur[v & 127], 1);
    esrc[base + p] = v >> 7;
  }
}

// ---------------- batched gather (bf16 rows): agg[i] = sum_{j->i} x[j] ----------------
template <int DIN>
__global__ void __launch_bounds__(256, 4)
k_gather(const int* __restrict__ rowstart,
         const int* __restrict__ deg,
         const int* __restrict__ esrc,
         const unsigned short* __restrict__ x,   // [N,DIN] bf16
         float* __restrict__ agg) {              // [N,DIN] f32
  constexpr int LPG = DIN / 4;            // 8 (DIN=32) / 16 (DIN=64)
  constexpr int GROUPS = 64 / LPG;        // 8 / 4
  constexpr int STEP = 16;
  constexpr int UNR = STEP / GROUPS;      // 2 / 4
  const int lane = threadIdx.x & 63;
  const int node = blockIdx.x * (blockDim.x >> 6) + (threadIdx.x >> 6);
  if (node >= N_NODES) return;
  const int sub = lane / LPG;
  const int lg = lane % LPG;
  const int rs = rowstart[node];
  const int dg = deg[node];
  float a0 = 0.f, a1 = 0.f, a2 = 0.f, a3 = 0.f;
  for (int base = 0; base < dg; base += 64) {
    const int lim = min(dg - base, 64);
    int myi = 0;
    if (lane < lim) myi = esrc[rs + base + lane];
    for (int j = 0; j < lim; j += STEP) {
      uint2 r[UNR];
      int e[UNR];
#pragma unroll
      for (int u = 0; u < UNR; ++u) {
        e[u] = j + u * GROUPS + sub;                      // always < 64
        int s = __shfl(myi, e[u]);
        r[u] = *((const uint2*)(x + (size_t)s * DIN) + lg);
      }
#pragma unroll
      for (int u = 0; u < UNR; ++u) {
        if (e[u] < lim) {
          a0 += bflo(r[u].x); a1 += bfhi(r[u].x);
          a2 += bflo(r[u].y); a3 += bfhi(r[u].y);
        }
      }
    }
  }
#pragma unroll
  for (int off = LPG; off < 64; off <<= 1) {
    a0 += __shfl_xor(a0, off);
    a1 += __shfl_xor(a1, off);
    a2 += __shfl_xor(a2, off);
    a3 += __shfl_xor(a3, off);
  }
  if (sub == 0)
    *((float4*)(agg + (size_t)node * DIN) + lg) = make_float4(a0, a1, a2, a3);
}

// ------- transform: relu(agg@Wrel^T + b + x@Wroot^T), weights in VGPRs -------
template <int DIN, bool FUSE_POOL>
__global__ void __launch_bounds__(256, 2)
k_transform(const float* __restrict__ agg,           // [N,DIN] f32
            const unsigned short* __restrict__ x,    // [N,DIN] bf16
            const float* __restrict__ wrel,          // [64,DIN]
            const float* __restrict__ brel,          // [64]
            const float* __restrict__ wroot,         // [64,DIN]
            const int* __restrict__ batch,
            void* __restrict__ outv) {  // bf16 [N,64] (conv1) or f32 [G,64] sums
  const int lane = threadIdx.x & 63;
  const int wid = blockIdx.x * (blockDim.x >> 6) + (threadIdx.x >> 6);
  const int nwaves = (gridDim.x * blockDim.x) >> 6;
  float wr[DIN], wo[DIN];
#pragma unroll
  for (int q = 0; q < DIN / 4; ++q) {
    float4 a = *((const float4*)(wrel + (size_t)lane * DIN) + q);
    wr[4 * q] = a.x; wr[4 * q + 1] = a.y; wr[4 * q + 2] = a.z; wr[4 * q + 3] = a.w;
    float4 b = *((const float4*)(wroot + (size_t)lane * DIN) + q);
    wo[4 * q] = b.x; wo[4 * q + 1] = b.y; wo[4 * q + 2] = b.z; wo[4 * q + 3] = b.w;
  }
  const float bias = brel[lane];
  for (int node = wid; node < N_NODES; node += nwaves) {
    const float4* ar = (const float4*)(agg + (size_t)node * DIN);
    const uint4* xr = (const uint4*)(x + (size_t)node * DIN);
    float acc = bias;
#pragma unroll
    for (int q = 0; q < DIN / 8; ++q) {
      uint4 bv = xr[q];                        // 8 bf16, wave-uniform broadcast
      float4 c0 = ar[2 * q], c1 = ar[2 * q + 1];
      acc = fmaf(c0.x, wr[8 * q + 0], acc);
      acc = fmaf(c0.y, wr[8 * q + 1], acc);
      acc = fmaf(c0.z, wr[8 * q + 2], acc);
      acc = fmaf(c0.w, wr[8 * q + 3], acc);
      acc = fmaf(c1.x, wr[8 * q + 4], acc);
      acc = fmaf(c1.y, wr[8 * q + 5], acc);
      acc = fmaf(c1.z, wr[8 * q + 6], acc);
      acc = fmaf(c1.w, wr[8 * q + 7], acc);
      acc = fmaf(bflo(bv.x), wo[8 * q + 0], acc);
      acc = fmaf(bfhi(bv.x), wo[8 * q + 1], acc);
      acc = fmaf(bflo(bv.y), wo[8 * q + 2], acc);
      acc = fmaf(bfhi(bv.y), wo[8 * q + 3], acc);
      acc = fmaf(bflo(bv.z), wo[8 * q + 4], acc);
      acc = fmaf(bfhi(bv.z), wo[8 * q + 5], acc);
      acc = fmaf(bflo(bv.w), wo[8 * q + 6], acc);
      acc = fmaf(bfhi(bv.w), wo[8 * q + 7], acc);
    }
    acc = fmaxf(acc, 0.f);
    if (FUSE_POOL) {
      atomicAdd((float*)outv + (size_t)batch[node] * 64 + lane, acc);
    } else {
      ((unsigned short*)outv)[(size_t)node * 64 + lane] = f2bf(acc);
    }
  }
}

// ---------------- per-graph node counts ----------------
__global__ void k_count(const int* __restrict__ batch, int* __restrict__ cnt) {
  int i = blockIdx.x * blockDim.x + threadIdx.x;
  if (i < N_NODES) atomicAdd(&cnt[batch[i]], 1);
}

// ---------------- classifier ----------------
__global__ void k_cls(const float* __restrict__ sums, const int* __restrict__ cnt,
                      const float* __restrict__ cw, const float* __restrict__ cb,
                      float* __restrict__ out) {
  int idx = blockIdx.x * blockDim.x + threadIdx.x;
  if (idx >= N_GRAPHS * 10) return;
  int g = idx / 10, c = idx - g * 10;
  float invc = 1.f / fmaxf((float)cnt[g], 1.f);
  float acc = 0.f;
#pragma unroll
  for (int d = 0; d < 64; ++d) acc = fmaf(sums[g * 64 + d], cw[c * 64 + d], acc);
  out[idx] = acc * invc + cb[c];
}

extern "C" void kernel_launch(void* const* d_in, const int* in_sizes, int n_in,
                              void* d_out, int out_size, void* d_ws, size_t ws_size,
                              hipStream_t stream) {
  const int*   tok    = (const int*)d_in[0];
  const int*   eidx   = (const int*)d_in[1];
  const int*   batch  = (const int*)d_in[2];
  const float* semb   = (const float*)d_in[3];
  const float* cemb   = (const float*)d_in[4];
  const float* lw     = (const float*)d_in[5];
  const float* lb     = (const float*)d_in[6];
  const float* w1rel  = (const float*)d_in[7];
  const float* b1     = (const float*)d_in[8];
  const float* w1root = (const float*)d_in[9];
  const float* w2rel  = (const float*)d_in[10];
  const float* b2     = (const float*)d_in[11];
  const float* w2root = (const float*)d_in[12];
  const float* cw     = (const float*)d_in[13];
  const float* cb     = (const float*)d_in[14];
  const int* src = eidx;
  const int* dst = eidx + N_EDGES;

  char* p = (char*)d_ws;
  unsigned short* x1 = (unsigned short*)p;  p += (size_t)N_NODES * 32 * 2;   // bf16
  unsigned short* x2 = (unsigned short*)p;  p += (size_t)N_NODES * 64 * 2;   // bf16
  float* aggb   = (float*)p;  p += (size_t)N_NODES * 64 * 4;
  int*   degv   = (int*)p;    p += (size_t)N_NODES * 4;
  int*   rowst  = (int*)p;    p += (size_t)N_NODES * 4;
  int*   tmp    = (int*)p;    p += (size_t)N_EDGES * 4;
  int*   esrc   = (int*)p;    p += (size_t)N_EDGES * 4;
  int*   bcnt   = (int*)p;    p += (size_t)NB * 64;    // 64B-padded counters
  int*   bcur   = (int*)p;    p += (size_t)NB * 64;    // 64B-padded cursors
  int*   bbase  = (int*)p;    p += 4096;
  float* sums   = (float*)p;  p += (size_t)N_GRAPHS * 64 * 4;
  int*   cnt    = (int*)p;    p += (size_t)N_GRAPHS * 4;

  hipMemsetAsync(bcnt, 0, (size_t)NB * 64, stream);
  hipMemsetAsync(sums, 0, (size_t)N_GRAPHS * 64 * 4 + (size_t)N_GRAPHS * 4, stream);

  k_embed_lin<<<(N_NODES + 255) / 256, 256, 0, stream>>>(tok, semb, cemb, lw, lb, x1);

  // Bucketed CSR build (782 buckets of 128 nodes), block-privatized fill
  k_bhist<<<306, 256, 0, stream>>>(dst, bcnt);
  k_bscan<<<1, 1024, 0, stream>>>(bcnt, bbase, bcur);
  k_bfill2<<<NBLK_FILL, 256, 0, stream>>>(src, dst, bcur, tmp);
  k_bfinal<<<NB, 256, 0, stream>>>(bbase, bcnt, tmp, degv, rowst, esrc);

  // conv1: gather x1 -> agg, transform -> x2 (bf16)
  k_gather<32><<<N_NODES / 4, 256, 0, stream>>>(rowst, degv, esrc, x1, aggb);
  k_transform<32, false><<<512, 256, 0, stream>>>(aggb, x1, w1rel, b1, w1root, nullptr, x2);

  // conv2: gather x2 -> agg, transform + fused mean-pool sums
  k_gather<64><<<N_NODES / 4, 256, 0, stream>>>(rowst, degv, esrc, x2, aggb);
  k_count<<<(N_NODES + 255) / 256, 256, 0, stream>>>(batch, cnt);
  k_transform<64, true><<<512, 256, 0, stream>>>(aggb, x2, w2rel, b2, w2root, batch, sums);

  k_cls<<<(N_GRAPHS * 10 + 255) / 256, 256, 0, stream>>>(sums, cnt, cw, cb, (float*)d_out);
}

// Round 6
// 216.531 us; speedup vs baseline: 3.0450x; 1.9488x over previous
//
#include <hip/hip_runtime.h>

#define N_NODES  100000
#define N_EDGES  1250000
#define N_GRAPHS 1024
#define NB       ((N_NODES + 127) >> 7)   // 782 buckets of 128 nodes
#define EPB      16384                     // edges per k_bfill2 block
#define NBLK_FILL ((N_EDGES + EPB - 1) / EPB)  // 77
#define N_TILES  (N_NODES / 16)            // 6250 MFMA row-tiles

typedef __attribute__((ext_vector_type(8))) short short8;
typedef __attribute__((ext_vector_type(4))) float f32x4;
union U16 { uint4 u; short8 s; };

// ---- bf16 helpers (round-to-nearest-even) ----
__device__ __forceinline__ float bflo(unsigned int w) { return __uint_as_float(w << 16); }
__device__ __forceinline__ float bfhi(unsigned int w) { return __uint_as_float(w & 0xffff0000u); }
__device__ __forceinline__ unsigned short f2bf(float f) {
  unsigned int u = __float_as_uint(f);
  u = (u + 0x7fffu + ((u >> 16) & 1u)) >> 16;
  return (unsigned short)u;
}

// ------- embed + linear (16 -> 32) + relu -> bf16 into F1 right half -------
__global__ void k_embed_lin(const int* __restrict__ tok,
                            const float* __restrict__ semb,
                            const float* __restrict__ cemb,
                            const float* __restrict__ lw,   // [32,16]
                            const float* __restrict__ lb,   // [32]
                            unsigned short* __restrict__ x1) {  // F1+32, row stride 64
  int i = blockIdx.x * blockDim.x + threadIdx.x;
  if (i >= N_NODES) return;
  int s = tok[2 * i], c = tok[2 * i + 1];
  float e[16];
#pragma unroll
  for (int k = 0; k < 8; ++k) { e[k] = semb[s * 8 + k]; e[8 + k] = cemb[c * 8 + k]; }
  unsigned int w[16];
#pragma unroll
  for (int o = 0; o < 16; ++o) {
    float a0 = lb[2 * o], a1 = lb[2 * o + 1];
#pragma unroll
    for (int k = 0; k < 16; ++k) {
      a0 = fmaf(e[k], lw[(2 * o) * 16 + k], a0);
      a1 = fmaf(e[k], lw[(2 * o + 1) * 16 + k], a1);
    }
    a0 = fmaxf(a0, 0.f); a1 = fmaxf(a1, 0.f);
    w[o] = (unsigned int)f2bf(a0) | ((unsigned int)f2bf(a1) << 16);
  }
  uint4* d4 = (uint4*)(x1 + (size_t)i * 64);
#pragma unroll
  for (int q = 0; q < 4; ++q) d4[q] = make_uint4(w[4 * q], w[4 * q + 1], w[4 * q + 2], w[4 * q + 3]);
}

// ------- bucket histogram (LDS-privatized; global counters 64B-padded) -------
__global__ void k_bhist(const int* __restrict__ dst, int* __restrict__ bcnt) {
  __shared__ int lh[NB];
  for (int i = threadIdx.x; i < NB; i += blockDim.x) lh[i] = 0;
  __syncthreads();
  for (int e = blockIdx.x * blockDim.x + threadIdx.x; e < N_EDGES; e += gridDim.x * blockDim.x)
    atomicAdd(&lh[dst[e] >> 7], 1);
  __syncthreads();
  for (int i = threadIdx.x; i < NB; i += blockDim.x) {
    int v = lh[i];
    if (v) atomicAdd(&bcnt[i * 16], v);   // one counter per cache line
  }
}

// ---------------- bucket scan: bases + padded cursors ----------------
__global__ void k_bscan(const int* __restrict__ bcnt, int* __restrict__ bbase,
                        int* __restrict__ bcur) {
  __shared__ int s[1024];
  int t = threadIdx.x;
  int d = (t < NB) ? bcnt[t * 16] : 0;
  s[t] = d;
  __syncthreads();
  for (int off = 1; off < 1024; off <<= 1) {
    int v = (t >= off) ? s[t - off] : 0;
    __syncthreads();
    s[t] += v;
    __syncthreads();
  }
  if (t < NB) { int excl = s[t] - d; bbase[t] = excl; bcur[t * 16] = excl; }
}

// ------- bucket fill, block-privatized: LDS hist -> 1 reservation/bucket -> scatter -------
__global__ void __launch_bounds__(256)
k_bfill2(const int* __restrict__ src, const int* __restrict__ dst,
         int* __restrict__ bcur, int* __restrict__ tmp) {
  __shared__ int h[NB];
  __shared__ int cur[NB];
  const int t = threadIdx.x;
  const int start = blockIdx.x * EPB;
  const int end = min(start + EPB, N_EDGES);
  for (int i = t; i < NB; i += 256) h[i] = 0;
  __syncthreads();
  for (int e = start + t; e < end; e += 256)
    atomicAdd(&h[dst[e] >> 7], 1);
  __syncthreads();
  for (int b = t; b < NB; b += 256) {
    int c = h[b];
    cur[b] = c ? atomicAdd(&bcur[b * 16], c) : 0;   // one global atomic per (block,bucket)
  }
  __syncthreads();
  for (int e = start + t; e < end; e += 256) {
    int d = dst[e];
    int pos = atomicAdd(&cur[d >> 7], 1);           // LDS cursor
    tmp[pos] = (src[e] << 7) | (d & 127);
  }
}

// ------- per-bucket finalize: deg/rowstart + esrc scatter (all LDS-local) -------
__global__ void k_bfinal(const int* __restrict__ bbase, const int* __restrict__ bcnt,
                         const int* __restrict__ tmp,
                         int* __restrict__ deg, int* __restrict__ rowst,
                         int* __restrict__ esrc) {
  __shared__ int h[128], sc[128], cur[128];
  const int t = threadIdx.x;
  const int b = blockIdx.x;
  const int base = bbase[b], cnt = bcnt[b * 16];
  if (t < 128) h[t] = 0;
  __syncthreads();
  for (int i = t; i < cnt; i += 256) atomicAdd(&h[tmp[base + i] & 127], 1);
  __syncthreads();
  if (t < 128) sc[t] = h[t];
  __syncthreads();
  for (int off = 1; off < 128; off <<= 1) {
    int v = 0;
    if (t < 128 && t >= off) v = sc[t - off];
    __syncthreads();
    if (t < 128) sc[t] += v;
    __syncthreads();
  }
  if (t < 128) {
    int excl = sc[t] - h[t];
    cur[t] = excl;
    int node = (b << 7) + t;
    if (node < N_NODES) { deg[node] = h[t]; rowst[node] = base + excl; }
  }
  __syncthreads();
  for (int i = t; i < cnt; i += 256) {
    int v = tmp[base + i];
    int p = atomicAdd(&cur[v & 127], 1);
    esrc[base + p] = v >> 7;
  }
}

// ---- batched gather (bf16 rows): agg[i] = sum_{j->i} x[j], written as bf16 ----
// x = right half of F (row stride XS), agg = left half of F (row stride XS).
template <int DIN, int XS>
__global__ void __launch_bounds__(256, 4)
k_gather(const int* __restrict__ rowstart,
         const int* __restrict__ deg,
         const int* __restrict__ esrc,
         const unsigned short* __restrict__ x,
         unsigned short* __restrict__ agg) {
  constexpr int LPG = DIN / 4;            // 8 (DIN=32) / 16 (DIN=64)
  constexpr int GROUPS = 64 / LPG;        // 8 / 4
  constexpr int STEP = 16;
  constexpr int UNR = STEP / GROUPS;      // 2 / 4
  const int lane = threadIdx.x & 63;
  const int node = blockIdx.x * (blockDim.x >> 6) + (threadIdx.x >> 6);
  if (node >= N_NODES) return;
  const int sub = lane / LPG;
  const int lg = lane % LPG;
  const int rs = rowstart[node];
  const int dg = deg[node];
  float a0 = 0.f, a1 = 0.f, a2 = 0.f, a3 = 0.f;
  for (int base = 0; base < dg; base += 64) {
    const int lim = min(dg - base, 64);
    int myi = 0;
    if (lane < lim) myi = esrc[rs + base + lane];
    for (int j = 0; j < lim; j += STEP) {
      uint2 r[UNR];
      int e[UNR];
#pragma unroll
      for (int u = 0; u < UNR; ++u) {
        e[u] = j + u * GROUPS + sub;                      // always < 64
        int s = __shfl(myi, e[u]);
        r[u] = *((const uint2*)(x + (size_t)s * XS) + lg);
      }
#pragma unroll
      for (int u = 0; u < UNR; ++u) {
        if (e[u] < lim) {
          a0 += bflo(r[u].x); a1 += bfhi(r[u].x);
          a2 += bflo(r[u].y); a3 += bfhi(r[u].y);
        }
      }
    }
  }
#pragma unroll
  for (int off = LPG; off < 64; off <<= 1) {
    a0 += __shfl_xor(a0, off);
    a1 += __shfl_xor(a1, off);
    a2 += __shfl_xor(a2, off);
    a3 += __shfl_xor(a3, off);
  }
  if (sub == 0) {
    uint2 w;
    w.x = (unsigned int)f2bf(a0) | ((unsigned int)f2bf(a1) << 16);
    w.y = (unsigned int)f2bf(a2) | ((unsigned int)f2bf(a3) << 16);
    *((uint2*)(agg + (size_t)node * XS) + lg) = w;
  }
}

// ------- pack Wcat = [wrel; wroot] (KDIM x 64) into MFMA B-fragments -------
// frag f=(kc*4+ct), lane l, elem e: Wcat[kc*32 + (l>>4)*8 + e][ct*16 + (l&15)]
template <int DIN>
__global__ void k_prep(const float* __restrict__ wrel, const float* __restrict__ wroot,
                       unsigned short* __restrict__ Bf) {
  constexpr int NKC = (2 * DIN) / 32;
  int t = blockIdx.x * blockDim.x + threadIdx.x;
  if (t >= NKC * 4 * 64) return;
  int l = t & 63;
  int ct = (t >> 6) & 3;
  int kc = t >> 8;
  int col = ct * 16 + (l & 15);
#pragma unroll
  for (int e = 0; e < 8; ++e) {
    int k = kc * 32 + ((l >> 4) << 3) + e;
    float v = (k < DIN) ? wrel[col * DIN + k] : wroot[col * DIN + (k - DIN)];
    Bf[(size_t)t * 8 + e] = f2bf(v);
  }
}

// ------- MFMA transform: Y = relu(F @ Wcat + bias), bf16 in/out, f32 accum -------
// One wave per 16-node tile. A: lane holds F[tile*16 + (l&15)][kc*32+(l>>4)*8 .. +7].
// C/D: col=lane&15, row=(lane>>4)*4+reg  (m89-verified).
template <int KDIM>
__global__ void __launch_bounds__(256)
k_mm(const unsigned short* __restrict__ F, const uint4* __restrict__ Bf,
     const float* __restrict__ bias, unsigned short* __restrict__ Y, int ys) {
  constexpr int NKC = KDIM / 32;
  const int lane = threadIdx.x & 63;
  const int tile = (blockIdx.x * blockDim.x + threadIdx.x) >> 6;
  short8 bf[NKC][4];
#pragma unroll
  for (int kc = 0; kc < NKC; ++kc)
#pragma unroll
    for (int ct = 0; ct < 4; ++ct) {
      U16 u; u.u = Bf[(kc * 4 + ct) * 64 + lane];
      bf[kc][ct] = u.s;
    }
  float bc[4];
#pragma unroll
  for (int ct = 0; ct < 4; ++ct) bc[ct] = bias[ct * 16 + (lane & 15)];
  if (tile >= N_TILES) return;
  const int row = tile * 16 + (lane & 15);
  short8 a[NKC];
#pragma unroll
  for (int kc = 0; kc < NKC; ++kc) {
    U16 u;
    u.u = *(const uint4*)(F + (size_t)row * KDIM + kc * 32 + ((lane >> 4) << 3));
    a[kc] = u.s;
  }
#pragma unroll
  for (int ct = 0; ct < 4; ++ct) {
    f32x4 acc = {bc[ct], bc[ct], bc[ct], bc[ct]};
#pragma unroll
    for (int kc = 0; kc < NKC; ++kc)
      acc = __builtin_amdgcn_mfma_f32_16x16x32_bf16(a[kc], bf[kc][ct], acc, 0, 0, 0);
    const int col = ct * 16 + (lane & 15);
#pragma unroll
    for (int j = 0; j < 4; ++j) {
      int grow = tile * 16 + ((lane >> 4) << 2) + j;
      Y[(size_t)grow * ys + col] = f2bf(fmaxf(acc[j], 0.f));
    }
  }
}

// ------- fused mean-pool + classifier: one block per graph, batch is sorted -------
__global__ void __launch_bounds__(256)
k_pool(const unsigned short* __restrict__ y2,   // [N,64] bf16
       const int* __restrict__ batch,
       const float* __restrict__ cw, const float* __restrict__ cb,
       float* __restrict__ out) {
  __shared__ float part[4][64];
  const int g = blockIdx.x;
  const int lane = threadIdx.x & 63;
  const int wv = threadIdx.x >> 6;
  int lo = 0, hi = N_NODES;
  while (lo < hi) { int m = (lo + hi) >> 1; if (batch[m] < g) lo = m + 1; else hi = m; }
  int lo2 = lo, hi2 = N_NODES;
  while (lo2 < hi2) { int m = (lo2 + hi2) >> 1; if (batch[m] < g + 1) lo2 = m + 1; else hi2 = m; }
  float s = 0.f;
  for (int r = lo + wv; r < lo2; r += 4)
    s += __uint_as_float((unsigned int)y2[(size_t)r * 64 + lane] << 16);
  part[wv][lane] = s;
  __syncthreads();
  if (wv == 0) {
    float p = part[0][lane] + part[1][lane] + part[2][lane] + part[3][lane];
    int c_ = lo2 - lo;
    p *= 1.f / (float)(c_ > 0 ? c_ : 1);
    for (int c = 0; c < 10; ++c) {
      float v = p * cw[c * 64 + lane];
#pragma unroll
      for (int off = 1; off < 64; off <<= 1) v += __shfl_xor(v, off);
      if (lane == 0) out[g * 10 + c] = v + cb[c];
    }
  }
}

extern "C" void kernel_launch(void* const* d_in, const int* in_sizes, int n_in,
                              void* d_out, int out_size, void* d_ws, size_t ws_size,
                              hipStream_t stream) {
  const int*   tok    = (const int*)d_in[0];
  const int*   eidx   = (const int*)d_in[1];
  const int*   batch  = (const int*)d_in[2];
  const float* semb   = (const float*)d_in[3];
  const float* cemb   = (const float*)d_in[4];
  const float* lw     = (const float*)d_in[5];
  const float* lb     = (const float*)d_in[6];
  const float* w1rel  = (const float*)d_in[7];
  const float* b1     = (const float*)d_in[8];
  const float* w1root = (const float*)d_in[9];
  const float* w2rel  = (const float*)d_in[10];
  const float* b2     = (const float*)d_in[11];
  const float* w2root = (const float*)d_in[12];
  const float* cw     = (const float*)d_in[13];
  const float* cb     = (const float*)d_in[14];
  const int* src = eidx;
  const int* dst = eidx + N_EDGES;

  char* p = (char*)d_ws;
  unsigned short* F1 = (unsigned short*)p;  p += (size_t)N_NODES * 64 * 2;   // [agg1|x1] bf16
  unsigned short* F2 = (unsigned short*)p;  p += (size_t)N_NODES * 128 * 2;  // [agg2|x2] bf16
  unsigned short* y2 = (unsigned short*)p;  p += (size_t)N_NODES * 64 * 2;   // conv2 out bf16
  int*   degv   = (int*)p;    p += (size_t)N_NODES * 4;
  int*   rowst  = (int*)p;    p += (size_t)N_NODES * 4;
  int*   tmp    = (int*)p;    p += (size_t)N_EDGES * 4;
  int*   esrc   = (int*)p;    p += (size_t)N_EDGES * 4;
  int*   bcnt   = (int*)p;    p += (size_t)NB * 64;    // 64B-padded counters
  int*   bcur   = (int*)p;    p += (size_t)NB * 64;    // 64B-padded cursors
  int*   bbase  = (int*)p;    p += 4096;
  unsigned short* Bf1 = (unsigned short*)p;  p += 512 * 8 * 2;   // 8KB
  unsigned short* Bf2 = (unsigned short*)p;  p += 1024 * 8 * 2;  // 16KB

  hipMemsetAsync(bcnt, 0, (size_t)NB * 64, stream);

  k_embed_lin<<<(N_NODES + 255) / 256, 256, 0, stream>>>(tok, semb, cemb, lw, lb, F1 + 32);

  // Bucketed CSR build (shared by both conv layers)
  k_bhist<<<306, 256, 0, stream>>>(dst, bcnt);
  k_bscan<<<1, 1024, 0, stream>>>(bcnt, bbase, bcur);
  k_bfill2<<<NBLK_FILL, 256, 0, stream>>>(src, dst, bcur, tmp);
  k_bfinal<<<NB, 256, 0, stream>>>(bbase, bcnt, tmp, degv, rowst, esrc);

  // Weight fragment packing (tiny)
  k_prep<32><<<2, 256, 0, stream>>>(w1rel, w1root, Bf1);
  k_prep<64><<<4, 256, 0, stream>>>(w2rel, w2root, Bf2);

  // conv1: gather x1 -> agg1 (F1 left half), MFMA transform -> x2 (F2 right half)
  k_gather<32, 64><<<N_NODES / 4, 256, 0, stream>>>(rowst, degv, esrc, F1 + 32, F1);
  k_mm<64><<<(N_TILES + 3) / 4, 256, 0, stream>>>(F1, (const uint4*)Bf1, b1, F2 + 64, 128);

  // conv2: gather x2 -> agg2 (F2 left half), MFMA transform -> y2
  k_gather<64, 128><<<N_NODES / 4, 256, 0, stream>>>(rowst, degv, esrc, F2 + 64, F2);
  k_mm<128><<<(N_TILES + 3) / 4, 256, 0, stream>>>(F2, (const uint4*)Bf2, b2, y2, 64);

  // fused mean-pool + classifier
  k_pool<<<N_GRAPHS, 256, 0, stream>>>(y2, batch, cw, cb, (float*)d_out);
}

// Round 7
// 169.584 us; speedup vs baseline: 3.8880x; 1.2768x over previous
//
#include <hip/hip_runtime.h>

#define N_NODES  100000
#define N_EDGES  1250000
#define N_GRAPHS 1024
#define NB       ((N_NODES + 127) >> 7)        // 782 buckets of 128 nodes
#define EPB      2048                           // edges per hist/fill block
#define NBLK_F   ((N_EDGES + EPB - 1) / EPB)    // 611 blocks
#define N_TILES  (N_NODES / 16)                 // 6250 MFMA row-tiles

typedef __attribute__((ext_vector_type(8))) short short8;
typedef __attribute__((ext_vector_type(4))) float f32x4;
union U16 { uint4 u; short8 s; };

// ---- bf16 helpers (round-to-nearest-even) ----
__device__ __forceinline__ float bflo(unsigned int w) { return __uint_as_float(w << 16); }
__device__ __forceinline__ float bfhi(unsigned int w) { return __uint_as_float(w & 0xffff0000u); }
__device__ __forceinline__ unsigned short f2bf(float f) {
  unsigned int u = __float_as_uint(f);
  u = (u + 0x7fffu + ((u >> 16) & 1u)) >> 16;
  return (unsigned short)u;
}

// ------- embed + linear (16 -> 32) + relu -> bf16 into F1 right half -------
__global__ void k_embed_lin(const int* __restrict__ tok,
                            const float* __restrict__ semb,
                            const float* __restrict__ cemb,
                            const float* __restrict__ lw,   // [32,16]
                            const float* __restrict__ lb,   // [32]
                            unsigned short* __restrict__ x1) {  // F1+32, row stride 64
  int i = blockIdx.x * blockDim.x + threadIdx.x;
  if (i >= N_NODES) return;
  int s = tok[2 * i], c = tok[2 * i + 1];
  float e[16];
#pragma unroll
  for (int k = 0; k < 8; ++k) { e[k] = semb[s * 8 + k]; e[8 + k] = cemb[c * 8 + k]; }
  unsigned int w[16];
#pragma unroll
  for (int o = 0; o < 16; ++o) {
    float a0 = lb[2 * o], a1 = lb[2 * o + 1];
#pragma unroll
    for (int k = 0; k < 16; ++k) {
      a0 = fmaf(e[k], lw[(2 * o) * 16 + k], a0);
      a1 = fmaf(e[k], lw[(2 * o + 1) * 16 + k], a1);
    }
    a0 = fmaxf(a0, 0.f); a1 = fmaxf(a1, 0.f);
    w[o] = (unsigned int)f2bf(a0) | ((unsigned int)f2bf(a1) << 16);
  }
  uint4* d4 = (uint4*)(x1 + (size_t)i * 64);
#pragma unroll
  for (int q = 0; q < 4; ++q) d4[q] = make_uint4(w[4 * q], w[4 * q + 1], w[4 * q + 2], w[4 * q + 3]);
}

// ------- per-block bucket histogram -> hist[bucket][block] (no global atomics) -------
__global__ void __launch_bounds__(256)
k_bhist2(const int* __restrict__ dst, int* __restrict__ hist) {
  __shared__ int lh[NB];
  const int t = threadIdx.x;
  const int blk = blockIdx.x;
  for (int i = t; i < NB; i += 256) lh[i] = 0;
  __syncthreads();
  const int start = blk * EPB;
  const int end = min(start + EPB, N_EDGES);
  for (int e = start + t; e < end; e += 256)
    atomicAdd(&lh[dst[e] >> 7], 1);
  __syncthreads();
  for (int i = t; i < NB; i += 256)
    hist[(size_t)i * NBLK_F + blk] = lh[i];
}

// ------- per-bucket exclusive scan across blocks (in place) + bucket totals -------
__global__ void __launch_bounds__(256)
k_colscan(int* __restrict__ hist, int* __restrict__ btotal) {
  __shared__ int part[256];
  const int b = blockIdx.x;
  int* row = hist + (size_t)b * NBLK_F;
  const int t = threadIdx.x;
  constexpr int C = (NBLK_F + 255) / 256;   // 3
  int v[C];
  int s = 0;
#pragma unroll
  for (int j = 0; j < C; ++j) {
    int idx = t * C + j;
    v[j] = (idx < NBLK_F) ? row[idx] : 0;
    s += v[j];
  }
  part[t] = s;
  __syncthreads();
  for (int off = 1; off < 256; off <<= 1) {
    int x = (t >= off) ? part[t - off] : 0;
    __syncthreads();
    part[t] += x;
    __syncthreads();
  }
  int run = part[t] - s;                    // exclusive prefix of this chunk
#pragma unroll
  for (int j = 0; j < C; ++j) {
    int idx = t * C + j;
    if (idx < NBLK_F) { int old = v[j]; row[idx] = run; run += old; }
  }
  if (t == 255) btotal[b] = part[255];
}

// ---------------- bucket-base scan ----------------
__global__ void k_bscan(const int* __restrict__ btotal, int* __restrict__ bbase) {
  __shared__ int s[1024];
  int t = threadIdx.x;
  int d = (t < NB) ? btotal[t] : 0;
  s[t] = d;
  __syncthreads();
  for (int off = 1; off < 1024; off <<= 1) {
    int v = (t >= off) ? s[t - off] : 0;
    __syncthreads();
    s[t] += v;
    __syncthreads();
  }
  if (t < NB) bbase[t] = s[t] - d;
}

// ------- fill: LDS cursors = bbase + scanned per-block offset; scatter -------
__global__ void __launch_bounds__(256)
k_bfill3(const int* __restrict__ src, const int* __restrict__ dst,
         const int* __restrict__ bbase, const int* __restrict__ hist,
         int* __restrict__ tmp) {
  __shared__ int cur[NB];
  const int t = threadIdx.x;
  const int blk = blockIdx.x;
  for (int i = t; i < NB; i += 256)
    cur[i] = bbase[i] + hist[(size_t)i * NBLK_F + blk];
  __syncthreads();
  const int start = blk * EPB;
  const int end = min(start + EPB, N_EDGES);
  for (int e = start + t; e < end; e += 256) {
    int d = dst[e];
    int pos = atomicAdd(&cur[d >> 7], 1);   // LDS cursor only
    tmp[pos] = (src[e] << 7) | (d & 127);
  }
}

// ------- per-bucket finalize: deg/rowstart + esrc scatter (all LDS-local) -------
__global__ void k_bfinal(const int* __restrict__ bbase, const int* __restrict__ btotal,
                         const int* __restrict__ tmp,
                         int* __restrict__ deg, int* __restrict__ rowst,
                         int* __restrict__ esrc) {
  __shared__ int h[128], sc[128], cur[128];
  const int t = threadIdx.x;
  const int b = blockIdx.x;
  const int base = bbase[b], cnt = btotal[b];
  if (t < 128) h[t] = 0;
  __syncthreads();
  for (int i = t; i < cnt; i += 256) atomicAdd(&h[tmp[base + i] & 127], 1);
  __syncthreads();
  if (t < 128) sc[t] = h[t];
  __syncthreads();
  for (int off = 1; off < 128; off <<= 1) {
    int v = 0;
    if (t < 128 && t >= off) v = sc[t - off];
    __syncthreads();
    if (t < 128) sc[t] += v;
    __syncthreads();
  }
  if (t < 128) {
    int excl = sc[t] - h[t];
    cur[t] = excl;
    int node = (b << 7) + t;
    if (node < N_NODES) { deg[node] = h[t]; rowst[node] = base + excl; }
  }
  __syncthreads();
  for (int i = t; i < cnt; i += 256) {
    int v = tmp[base + i];
    int p = atomicAdd(&cur[v & 127], 1);
    esrc[base + p] = v >> 7;
  }
}

// ---- batched gather (bf16 rows): agg[i] = sum_{j->i} x[j], written as bf16 ----
template <int DIN, int XS>
__global__ void __launch_bounds__(256, 4)
k_gather(const int* __restrict__ rowstart,
         const int* __restrict__ deg,
         const int* __restrict__ esrc,
         const unsigned short* __restrict__ x,
         unsigned short* __restrict__ agg) {
  constexpr int LPG = DIN / 4;            // 8 (DIN=32) / 16 (DIN=64)
  constexpr int GROUPS = 64 / LPG;        // 8 / 4
  constexpr int STEP = 16;
  constexpr int UNR = STEP / GROUPS;      // 2 / 4
  const int lane = threadIdx.x & 63;
  const int node = blockIdx.x * (blockDim.x >> 6) + (threadIdx.x >> 6);
  if (node >= N_NODES) return;
  const int sub = lane / LPG;
  const int lg = lane % LPG;
  const int rs = rowstart[node];
  const int dg = deg[node];
  float a0 = 0.f, a1 = 0.f, a2 = 0.f, a3 = 0.f;
  for (int base = 0; base < dg; base += 64) {
    const int lim = min(dg - base, 64);
    int myi = 0;
    if (lane < lim) myi = esrc[rs + base + lane];
    for (int j = 0; j < lim; j += STEP) {
      uint2 r[UNR];
      int e[UNR];
#pragma unroll
      for (int u = 0; u < UNR; ++u) {
        e[u] = j + u * GROUPS + sub;                      // always < 64
        int s = __shfl(myi, e[u]);
        r[u] = *((const uint2*)(x + (size_t)s * XS) + lg);
      }
#pragma unroll
      for (int u = 0; u < UNR; ++u) {
        if (e[u] < lim) {
          a0 += bflo(r[u].x); a1 += bfhi(r[u].x);
          a2 += bflo(r[u].y); a3 += bfhi(r[u].y);
        }
      }
    }
  }
#pragma unroll
  for (int off = LPG; off < 64; off <<= 1) {
    a0 += __shfl_xor(a0, off);
    a1 += __shfl_xor(a1, off);
    a2 += __shfl_xor(a2, off);
    a3 += __shfl_xor(a3, off);
  }
  if (sub == 0) {
    uint2 w;
    w.x = (unsigned int)f2bf(a0) | ((unsigned int)f2bf(a1) << 16);
    w.y = (unsigned int)f2bf(a2) | ((unsigned int)f2bf(a3) << 16);
    *((uint2*)(agg + (size_t)node * XS) + lg) = w;
  }
}

// ------- pack Wcat = [wrel; wroot] (KDIM x 64) into MFMA B-fragments -------
template <int DIN>
__global__ void k_prep(const float* __restrict__ wrel, const float* __restrict__ wroot,
                       unsigned short* __restrict__ Bf) {
  constexpr int NKC = (2 * DIN) / 32;
  int t = blockIdx.x * blockDim.x + threadIdx.x;
  if (t >= NKC * 4 * 64) return;
  int l = t & 63;
  int ct = (t >> 6) & 3;
  int kc = t >> 8;
  int col = ct * 16 + (l & 15);
#pragma unroll
  for (int e = 0; e < 8; ++e) {
    int k = kc * 32 + ((l >> 4) << 3) + e;
    float v = (k < DIN) ? wrel[col * DIN + k] : wroot[col * DIN + (k - DIN)];
    Bf[(size_t)t * 8 + e] = f2bf(v);
  }
}

// ------- MFMA transform: Y = relu(F @ Wcat + bias), bf16 in/out, f32 accum -------
template <int KDIM>
__global__ void __launch_bounds__(256)
k_mm(const unsigned short* __restrict__ F, const uint4* __restrict__ Bf,
     const float* __restrict__ bias, unsigned short* __restrict__ Y, int ys) {
  constexpr int NKC = KDIM / 32;
  const int lane = threadIdx.x & 63;
  const int tile = (blockIdx.x * blockDim.x + threadIdx.x) >> 6;
  short8 bf[NKC][4];
#pragma unroll
  for (int kc = 0; kc < NKC; ++kc)
#pragma unroll
    for (int ct = 0; ct < 4; ++ct) {
      U16 u; u.u = Bf[(kc * 4 + ct) * 64 + lane];
      bf[kc][ct] = u.s;
    }
  float bc[4];
#pragma unroll
  for (int ct = 0; ct < 4; ++ct) bc[ct] = bias[ct * 16 + (lane & 15)];
  if (tile >= N_TILES) return;
  const int row = tile * 16 + (lane & 15);
  short8 a[NKC];
#pragma unroll
  for (int kc = 0; kc < NKC; ++kc) {
    U16 u;
    u.u = *(const uint4*)(F + (size_t)row * KDIM + kc * 32 + ((lane >> 4) << 3));
    a[kc] = u.s;
  }
#pragma unroll
  for (int ct = 0; ct < 4; ++ct) {
    f32x4 acc = {bc[ct], bc[ct], bc[ct], bc[ct]};
#pragma unroll
    for (int kc = 0; kc < NKC; ++kc)
      acc = __builtin_amdgcn_mfma_f32_16x16x32_bf16(a[kc], bf[kc][ct], acc, 0, 0, 0);
    const int col = ct * 16 + (lane & 15);
#pragma unroll
    for (int j = 0; j < 4; ++j) {
      int grow = tile * 16 + ((lane >> 4) << 2) + j;
      Y[(size_t)grow * ys + col] = f2bf(fmaxf(acc[j], 0.f));
    }
  }
}

// ------- fused mean-pool + classifier: one block per graph, batch is sorted -------
__global__ void __launch_bounds__(256)
k_pool(const unsigned short* __restrict__ y2,   // [N,64] bf16
       const int* __restrict__ batch,
       const float* __restrict__ cw, const float* __restrict__ cb,
       float* __restrict__ out) {
  __shared__ float part[4][64];
  const int g = blockIdx.x;
  const int lane = threadIdx.x & 63;
  const int wv = threadIdx.x >> 6;
  int lo = 0, hi = N_NODES;
  while (lo < hi) { int m = (lo + hi) >> 1; if (batch[m] < g) lo = m + 1; else hi = m; }
  int lo2 = lo, hi2 = N_NODES;
  while (lo2 < hi2) { int m = (lo2 + hi2) >> 1; if (batch[m] < g + 1) lo2 = m + 1; else hi2 = m; }
  float s = 0.f;
  for (int r = lo + wv; r < lo2; r += 4)
    s += __uint_as_float((unsigned int)y2[(size_t)r * 64 + lane] << 16);
  part[wv][lane] = s;
  __syncthreads();
  if (wv == 0) {
    float p = part[0][lane] + part[1][lane] + part[2][lane] + part[3][lane];
    int c_ = lo2 - lo;
    p *= 1.f / (float)(c_ > 0 ? c_ : 1);
    for (int c = 0; c < 10; ++c) {
      float v = p * cw[c * 64 + lane];
#pragma unroll
      for (int off = 1; off < 64; off <<= 1) v += __shfl_xor(v, off);
      if (lane == 0) out[g * 10 + c] = v + cb[c];
    }
  }
}

extern "C" void kernel_launch(void* const* d_in, const int* in_sizes, int n_in,
                              void* d_out, int out_size, void* d_ws, size_t ws_size,
                              hipStream_t stream) {
  const int*   tok    = (const int*)d_in[0];
  const int*   eidx   = (const int*)d_in[1];
  const int*   batch  = (const int*)d_in[2];
  const float* semb   = (const float*)d_in[3];
  const float* cemb   = (const float*)d_in[4];
  const float* lw     = (const float*)d_in[5];
  const float* lb     = (const float*)d_in[6];
  const float* w1rel  = (const float*)d_in[7];
  const float* b1     = (const float*)d_in[8];
  const float* w1root = (const float*)d_in[9];
  const float* w2rel  = (const float*)d_in[10];
  const float* b2     = (const float*)d_in[11];
  const float* w2root = (const float*)d_in[12];
  const float* cw     = (const float*)d_in[13];
  const float* cb     = (const float*)d_in[14];
  const int* src = eidx;
  const int* dst = eidx + N_EDGES;

  char* p = (char*)d_ws;
  unsigned short* F1 = (unsigned short*)p;  p += (size_t)N_NODES * 64 * 2;   // [agg1|x1] bf16
  unsigned short* F2 = (unsigned short*)p;  p += (size_t)N_NODES * 128 * 2;  // [agg2|x2] bf16
  unsigned short* y2 = (unsigned short*)p;  p += (size_t)N_NODES * 64 * 2;   // conv2 out bf16
  int*   degv   = (int*)p;    p += (size_t)N_NODES * 4;
  int*   rowst  = (int*)p;    p += (size_t)N_NODES * 4;
  int*   tmp    = (int*)p;    p += (size_t)N_EDGES * 4;
  int*   esrc   = (int*)p;    p += (size_t)N_EDGES * 4;
  int*   hist   = (int*)p;    p += (size_t)NB * NBLK_F * 4;   // [bucket][block]
  int*   btotal = (int*)p;    p += 4096;
  int*   bbase  = (int*)p;    p += 4096;
  unsigned short* Bf1 = (unsigned short*)p;  p += 512 * 8 * 2;   // 8KB
  unsigned short* Bf2 = (unsigned short*)p;  p += 1024 * 8 * 2;  // 16KB

  k_embed_lin<<<(N_NODES + 255) / 256, 256, 0, stream>>>(tok, semb, cemb, lw, lb, F1 + 32);

  // Deterministic counting-sort CSR build (no global atomics)
  k_bhist2<<<NBLK_F, 256, 0, stream>>>(dst, hist);
  k_colscan<<<NB, 256, 0, stream>>>(hist, btotal);
  k_bscan<<<1, 1024, 0, stream>>>(btotal, bbase);
  k_bfill3<<<NBLK_F, 256, 0, stream>>>(src, dst, bbase, hist, tmp);
  k_bfinal<<<NB, 256, 0, stream>>>(bbase, btotal, tmp, degv, rowst, esrc);

  // Weight fragment packing (tiny)
  k_prep<32><<<2, 256, 0, stream>>>(w1rel, w1root, Bf1);
  k_prep<64><<<4, 256, 0, stream>>>(w2rel, w2root, Bf2);

  // conv1: gather x1 -> agg1 (F1 left half), MFMA transform -> x2 (F2 right half)
  k_gather<32, 64><<<N_NODES / 4, 256, 0, stream>>>(rowst, degv, esrc, F1 + 32, F1);
  k_mm<64><<<(N_TILES + 3) / 4, 256, 0, stream>>>(F1, (const uint4*)Bf1, b1, F2 + 64, 128);

  // conv2: gather x2 -> agg2 (F2 left half), MFMA transform -> y2
  k_gather<64, 128><<<N_NODES / 4, 256, 0, stream>>>(rowst, degv, esrc, F2 + 64, F2);
  k_mm<128><<<(N_TILES + 3) / 4, 256, 0, stream>>>(F2, (const uint4*)Bf2, b2, y2, 64);

  // fused mean-pool + classifier
  k_pool<<<N_GRAPHS, 256, 0, stream>>>(y2, batch, cw, cb, (float*)d_out);
}